// Round 5
// baseline (579.742 us; speedup 1.0000x reference)
//
#include <hip/hip_runtime.h>
#include <hip/hip_bf16.h>

#define R_REL   8
#define C_DIM   64
#define K_DIM   576      // (R_REL+1)*C_DIM
#define KT_N    18       // K_DIM / 32
#define CT_N    4        // C_DIM / 16
#define TILE_M  16
#define K_PAD   584      // 576 + 8 bf16 pad -> row stride 1168 B

typedef __attribute__((ext_vector_type(8))) short bf16x8;
typedef __attribute__((ext_vector_type(4))) float f32x4;

static __device__ __forceinline__ unsigned short f2bf(float f) {
    union { float f; unsigned u; } v; v.f = f;
    unsigned r = v.u + 0x7FFFu + ((v.u >> 16) & 1u);   // RNE
    return (unsigned short)(r >> 16);
}
static __device__ __forceinline__ float bf2f(unsigned u16) {
    union { unsigned u; float f; } v; v.u = u16 << 16;
    return v.f;
}

// Pack W [9][64][64] f32 -> bf16 MFMA B-fragments.
__global__ void pack_w_kernel(const float* __restrict__ w, unsigned int* __restrict__ wf) {
    int t = blockIdx.x * blockDim.x + threadIdx.x;
    if (t >= KT_N * CT_N * 64) return;
    int lane = t & 63;
    int ct   = (t >> 6) & 3;
    int kt   = t >> 8;
    int row0 = kt * 32 + (lane >> 4) * 8;
    int col  = ct * 16 + (lane & 15);
    unsigned short v[8];
#pragma unroll
    for (int j = 0; j < 8; ++j)
        v[j] = f2bf(w[(row0 + j) * C_DIM + col]);
    uint4 o;
    o.x = (unsigned)v[0] | ((unsigned)v[1] << 16);
    o.y = (unsigned)v[2] | ((unsigned)v[3] << 16);
    o.z = (unsigned)v[4] | ((unsigned)v[5] << 16);
    o.w = (unsigned)v[6] | ((unsigned)v[7] << 16);
    ((uint4*)wf)[t] = o;
}

// x_feat f32 -> bf16 so each edge gather reads 128B not 256B.
__global__ void cvt_x_kernel(const float* __restrict__ x, unsigned short* __restrict__ xb,
                             int n4) {
    int i = blockIdx.x * blockDim.x + threadIdx.x;
    if (i >= n4) return;
    float4 v = ((const float4*)x)[i];
    ushort4 o;
    o.x = f2bf(v.x); o.y = f2bf(v.y); o.z = f2bf(v.z); o.w = f2bf(v.w);
    ((ushort4*)xb)[i] = o;
}

#define ACCUM_SWITCH(RELV, VV)                                  \
    switch (RELV) {                                             \
        case 0: s0 += (VV); ++c0; break;                        \
        case 1: s1 += (VV); ++c1; break;                        \
        case 2: s2 += (VV); ++c2; break;                        \
        case 3: s3 += (VV); ++c3; break;                        \
        case 4: s4 += (VV); ++c4; break;                        \
        case 5: s5 += (VV); ++c5; break;                        \
        case 6: s6 += (VV); ++c6; break;                        \
        default: s7 += (VV); ++c7; break;                       \
    }

template<int USE_BF>
__global__ __launch_bounds__(256, 8) void rgcn_kernel(
    const float* __restrict__ x_feat,
    const unsigned short* __restrict__ xb,
    const float* __restrict__ bias,
    const int*   __restrict__ row_ptr,
    const int*   __restrict__ col_ind,
    const int*   __restrict__ edge_type,
    const unsigned short* __restrict__ wfrag,
    float* __restrict__ out,
    int n_nodes)
{
    __shared__ __align__(16) float          bins[TILE_M * R_REL * C_DIM]; // 32 KB
    __shared__ __align__(16) unsigned short xa[TILE_M][K_PAD];            // 18.7 KB
    const int tid   = threadIdx.x;
    const int lane  = tid & 63;
    const int w     = tid >> 6;            // wave id 0..3
    const int m0    = blockIdx.x * TILE_M;
    const int nbase = m0 + w * 4;          // this wave's 4 nodes

    // ---- zero bins ----
#pragma unroll
    for (int i = 0; i < 8; ++i)
        ((float4*)bins)[tid * 8 + i] = make_float4(0.f, 0.f, 0.f, 0.f);
    __syncthreads();

    // ---- per-lane index prefetch: lane handles edge (lane&15) of node (lane>>4) ----
    const int n_l   = nbase + (lane >> 4);
    const bool v_l  = n_l < n_nodes;
    int rp0 = v_l ? row_ptr[n_l]     : 0;
    int rp1 = v_l ? row_ptr[n_l + 1] : 0;
    int deg_l = v_l ? (rp1 - rp0) : -1;
    int col_l = col_ind[rp0 + (lane & 15)];
    int rel_l = edge_type[rp0 + (lane & 15)];
    unsigned packed = ((unsigned)col_l << 3) | (unsigned)(rel_l & 7);

    // rel masks for counts (computed in uniform flow, before divergence)
    unsigned long long rmask[8];
#pragma unroll
    for (int r = 0; r < 8; ++r)
        rmask[r] = __ballot(rel_l == r);

    const bool fast = USE_BF && (__ballot(deg_l == 16) == ~0ull);

    if (fast) {
        // ---- gather + LDS-atomic binning, pipelined 2 nodes deep ----
        unsigned short uvA[16], uvB[16], selfv[4];

#define LOADN(MI, UV)                                                          \
        _Pragma("unroll")                                                      \
        for (int e = 0; e < 16; ++e) {                                         \
            int s = __builtin_amdgcn_readlane(packed, (MI) * 16 + e);          \
            UV[e] = xb[(size_t)(s >> 3) * C_DIM + lane];                       \
        }

#define PROCN(MI, UV)                                                          \
        _Pragma("unroll")                                                      \
        for (int e = 0; e < 16; ++e) {                                         \
            int s = __builtin_amdgcn_readlane(packed, (MI) * 16 + e);          \
            atomicAdd(&bins[((w * 4 + (MI)) << 9) + ((s & 7) << 6) + lane],    \
                      bf2f(UV[e]));                                            \
        }

        LOADN(0, uvA)
        LOADN(1, uvB)
#pragma unroll
        for (int mi = 0; mi < 4; ++mi)
            selfv[mi] = xb[(size_t)(nbase + mi) * C_DIM + lane];
        PROCN(0, uvA)
        LOADN(2, uvA)
        PROCN(1, uvB)
        LOADN(3, uvB)
        PROCN(2, uvA)
        PROCN(3, uvB)
#pragma unroll
        for (int mi = 0; mi < 4; ++mi)
            xa[w * 4 + mi][8 * C_DIM + lane] = selfv[mi];
#undef LOADN
#undef PROCN
    } else {
        // ---- general path: serial accumulate straight into xa ----
#pragma unroll
        for (int mi_ = 0; mi_ < 4; ++mi_) {
            const int mi = w * 4 + mi_;
            const int n  = nbase + mi_;
            const int sdeg  = __builtin_amdgcn_readlane(deg_l, mi_ * 16);
            const int sbase = __builtin_amdgcn_readlane(rp0,   mi_ * 16);
            if (sdeg < 0) {
                for (int k = lane; k < K_DIM; k += 64) xa[mi][k] = 0;
                continue;
            }
            float s0=0,s1=0,s2=0,s3=0,s4=0,s5=0,s6=0,s7=0;
            int   c0=0,c1=0,c2=0,c3=0,c4=0,c5=0,c6=0,c7=0;
            for (int e = 0; e < sdeg; ++e) {
                int src = col_ind[sbase + e];
                int rl  = edge_type[sbase + e];
                float vv = USE_BF ? bf2f(xb[(size_t)src * C_DIM + lane])
                                  : x_feat[(size_t)src * C_DIM + lane];
                ACCUM_SWITCH(rl, vv)
            }
            xa[mi][0*C_DIM+lane] = f2bf(s0 * __fdividef(1.0f, (float)(c0>0?c0:1)));
            xa[mi][1*C_DIM+lane] = f2bf(s1 * __fdividef(1.0f, (float)(c1>0?c1:1)));
            xa[mi][2*C_DIM+lane] = f2bf(s2 * __fdividef(1.0f, (float)(c2>0?c2:1)));
            xa[mi][3*C_DIM+lane] = f2bf(s3 * __fdividef(1.0f, (float)(c3>0?c3:1)));
            xa[mi][4*C_DIM+lane] = f2bf(s4 * __fdividef(1.0f, (float)(c4>0?c4:1)));
            xa[mi][5*C_DIM+lane] = f2bf(s5 * __fdividef(1.0f, (float)(c5>0?c5:1)));
            xa[mi][6*C_DIM+lane] = f2bf(s6 * __fdividef(1.0f, (float)(c6>0?c6:1)));
            xa[mi][7*C_DIM+lane] = f2bf(s7 * __fdividef(1.0f, (float)(c7>0?c7:1)));
            xa[mi][8*C_DIM+lane] = USE_BF ? (unsigned short)xb[(size_t)n * C_DIM + lane]
                                          : f2bf(x_feat[(size_t)n * C_DIM + lane]);
        }
    }
    __syncthreads();

    // ---- normalize bins -> xa (fast path only; wave handles its 4 nodes) ----
    if (fast) {
#pragma unroll
        for (int mi_ = 0; mi_ < 4; ++mi_) {
            const unsigned long long nodemask = 0xFFFFull << (mi_ * 16);
#pragma unroll
            for (int r = 0; r < 8; ++r) {
                int cnt = __popcll(rmask[r] & nodemask);
                float inv = __fdividef(1.0f, (float)(cnt > 0 ? cnt : 1));
                float vv  = bins[((w * 4 + mi_) << 9) + (r << 6) + lane] * inv;
                xa[w * 4 + mi_][r * C_DIM + lane] = f2bf(vv);
            }
        }
    }
    __syncthreads();

    // ---- phase 2: [16 x 576] @ [576 x 64]; wave w owns C-tile ct=w ----
    const int ct   = w;
    f32x4 acc = {0,0,0,0};
    const int arow = lane & 15;
    const int kgrp = lane >> 4;
    const bf16x8* wf8 = (const bf16x8*)wfrag;
#pragma unroll
    for (int kt = 0; kt < KT_N; ++kt) {
        bf16x8 a = *(const bf16x8*)&xa[arow][kt * 32 + kgrp * 8];
        acc = __builtin_amdgcn_mfma_f32_16x16x32_bf16(a, wf8[(kt*4 + ct)*64 + lane], acc, 0,0,0);
    }

    // ---- epilogue ----
    const int col   = ct * 16 + (lane & 15);
    const float b   = bias[col];
    const int rbase = (lane >> 4) * 4;
#pragma unroll
    for (int j = 0; j < 4; ++j) {
        int n = m0 + rbase + j;
        if (n < n_nodes)
            out[n * C_DIM + col] = acc[j] + b;
    }
}

extern "C" void kernel_launch(void* const* d_in, const int* in_sizes, int n_in,
                              void* d_out, int out_size, void* d_ws, size_t ws_size,
                              hipStream_t stream) {
    const float* x_feat    = (const float*)d_in[0];
    const float* weight    = (const float*)d_in[1];
    const float* bias      = (const float*)d_in[2];
    const int*   row_ptr   = (const int*)d_in[3];
    const int*   col_ind   = (const int*)d_in[4];
    const int*   edge_type = (const int*)d_in[5];
    float* out = (float*)d_out;

    const int n_nodes = in_sizes[3] - 1;
    const int nblocks = (n_nodes + TILE_M - 1) / TILE_M;

    unsigned int* wfrag = (unsigned int*)d_ws;              // 73728 bytes
    const size_t wf_bytes = (size_t)KT_N * CT_N * 64 * 16;  // 73728
    const size_t xb_bytes = (size_t)n_nodes * C_DIM * 2;

    pack_w_kernel<<<(KT_N * CT_N * 64 + 255) / 256, 256, 0, stream>>>(weight, wfrag);

    if (ws_size >= wf_bytes + xb_bytes) {
        unsigned short* xb = (unsigned short*)((char*)d_ws + wf_bytes);
        int n4 = n_nodes * C_DIM / 4;
        cvt_x_kernel<<<(n4 + 255) / 256, 256, 0, stream>>>(x_feat, xb, n4);
        rgcn_kernel<1><<<nblocks, 256, 0, stream>>>(x_feat, xb, bias, row_ptr, col_ind,
                                                    edge_type, (const unsigned short*)d_ws,
                                                    out, n_nodes);
    } else {
        rgcn_kernel<0><<<nblocks, 256, 0, stream>>>(x_feat, nullptr, bias, row_ptr, col_ind,
                                                    edge_type, (const unsigned short*)d_ws,
                                                    out, n_nodes);
    }
}

// Round 7
// 59.299 us; speedup vs baseline: 9.7765x; 9.7765x over previous
//
#include <hip/hip_runtime.h>
#include <hip/hip_bf16.h>

#define R_REL   8
#define C_DIM   64
#define K_DIM   576      // (R_REL+1)*C_DIM
#define KT_N    18       // K_DIM / 32
#define CT_N    4        // C_DIM / 16
#define TILE_M  16
#define K_PAD   584      // 576 + 8 bf16 pad -> row stride 1168 B (73*16B)

typedef __attribute__((ext_vector_type(8))) short bf16x8;
typedef __attribute__((ext_vector_type(4))) float f32x4;
typedef __attribute__((ext_vector_type(2))) unsigned u32x2;

static __device__ __forceinline__ unsigned short f2bf(float f) {
    union { float f; unsigned u; } v; v.f = f;
    unsigned r = v.u + 0x7FFFu + ((v.u >> 16) & 1u);   // RNE
    return (unsigned short)(r >> 16);
}
static __device__ __forceinline__ float bf2f(unsigned u16) {
    union { unsigned u; float f; } v; v.u = u16 << 16;
    return v.f;
}

// Pack W [9][64][64] f32 -> bf16 MFMA B-fragments.
__global__ void pack_w_kernel(const float* __restrict__ w, unsigned int* __restrict__ wf) {
    int t = blockIdx.x * blockDim.x + threadIdx.x;
    if (t >= KT_N * CT_N * 64) return;
    int lane = t & 63;
    int ct   = (t >> 6) & 3;
    int kt   = t >> 8;
    int row0 = kt * 32 + (lane >> 4) * 8;
    int col  = ct * 16 + (lane & 15);
    unsigned short v[8];
#pragma unroll
    for (int j = 0; j < 8; ++j)
        v[j] = f2bf(w[(row0 + j) * C_DIM + col]);
    uint4 o;
    o.x = (unsigned)v[0] | ((unsigned)v[1] << 16);
    o.y = (unsigned)v[2] | ((unsigned)v[3] << 16);
    o.z = (unsigned)v[4] | ((unsigned)v[5] << 16);
    o.w = (unsigned)v[6] | ((unsigned)v[7] << 16);
    ((uint4*)wf)[t] = o;
}

// x_feat f32 -> bf16 so each edge row is 128B not 256B.
__global__ void cvt_x_kernel(const float* __restrict__ x, unsigned short* __restrict__ xb,
                             int n4) {
    int i = blockIdx.x * blockDim.x + threadIdx.x;
    if (i >= n4) return;
    float4 v = ((const float4*)x)[i];
    ushort4 o;
    o.x = f2bf(v.x); o.y = f2bf(v.y); o.z = f2bf(v.z); o.w = f2bf(v.w);
    ((ushort4*)xb)[i] = o;
}

#define ACCUM_SWITCH(RELV, VV)                                  \
    switch (RELV) {                                             \
        case 0: s0 += (VV); ++c0; break;                        \
        case 1: s1 += (VV); ++c1; break;                        \
        case 2: s2 += (VV); ++c2; break;                        \
        case 3: s3 += (VV); ++c3; break;                        \
        case 4: s4 += (VV); ++c4; break;                        \
        case 5: s5 += (VV); ++c5; break;                        \
        case 6: s6 += (VV); ++c6; break;                        \
        default: s7 += (VV); ++c7; break;                       \
    }

template<int USE_BF>
__global__ __launch_bounds__(256, 4) void rgcn_kernel(
    const float* __restrict__ x_feat,
    const unsigned short* __restrict__ xb,
    const float* __restrict__ bias,
    const int*   __restrict__ row_ptr,
    const int*   __restrict__ col_ind,
    const int*   __restrict__ edge_type,
    const unsigned short* __restrict__ wfrag,
    float* __restrict__ out,
    int n_nodes)
{
    __shared__ __align__(16) unsigned short xa[TILE_M][K_PAD];   // 18.7 KB
    __shared__ __align__(16) int            col_lds[4][64];      // 1 KB
    __shared__ __align__(8)  unsigned char  rel_lds[4][64];      // 256 B
    __shared__ __align__(4)  unsigned short inv_lds[4][32];      // 256 B

    const int tid   = threadIdx.x;
    const int lane  = tid & 63;
    const int w     = tid >> 6;            // wave id 0..3
    const int m0    = blockIdx.x * TILE_M;
    const int nbase = m0 + w * 4;          // this wave's 4 nodes

    // ---- per-lane meta: lane = local_node(2b)*16 + edge_slot(4b) ----
    const int n_l   = nbase + (lane >> 4);
    const bool v_l  = n_l < n_nodes;
    int rp0   = v_l ? row_ptr[n_l]     : 0;
    int rp1   = v_l ? row_ptr[n_l + 1] : 0;
    int deg_l = v_l ? (rp1 - rp0) : -1;
    int col_l = col_ind[rp0 + (lane & 15)];
    int rel_l = edge_type[rp0 + (lane & 15)];

    const bool fast = USE_BF && (__ballot(deg_l == 16) == ~0ull);

    if (fast) {
        // ---- publish per-wave edge tables ----
        col_lds[w][lane] = col_l;
        rel_lds[w][lane] = (unsigned char)rel_l;
        unsigned long long bsel = 0;
#pragma unroll
        for (int r = 0; r < 8; ++r) {
            unsigned long long b = __ballot(rel_l == r);
            bsel = ((lane & 7) == r) ? b : bsel;
        }
        if (lane < 32) {
            int nd  = (lane >> 3) & 3;
            int cnt = __popcll(bsel & (0xFFFFull << (nd * 16)));
            inv_lds[w][lane] = f2bf(1.0f / (float)(cnt > 0 ? cnt : 1));
        }

        // ---- self row straight into xa ----
        u32x2 selfv = *(const u32x2*)(xb + (size_t)(nbase + (lane >> 4)) * C_DIM
                                      + (lane & 15) * 4);
        *(u32x2*)&xa[w * 4 + (lane >> 4)][8 * C_DIM + (lane & 15) * 4] = selfv;

        // ---- read back the 16 src indices this lane's B-fragments need ----
        const int q8 = (lane >> 4) * 8;
        int4 c0a = *(const int4*)&col_lds[w][q8];
        int4 c0b = *(const int4*)&col_lds[w][q8 + 4];
        int4 c1a = *(const int4*)&col_lds[w][32 + q8];
        int4 c1b = *(const int4*)&col_lds[w][32 + q8 + 4];
        int src0[8] = {c0a.x, c0a.y, c0a.z, c0a.w, c0b.x, c0b.y, c0b.z, c0b.w};
        int src1[8] = {c1a.x, c1a.y, c1a.z, c1a.w, c1b.x, c1b.y, c1b.z, c1b.w};

        // ---- direct B-fragment gather: bw[pr][g][d] = {X[e=2d][ch], X[e=2d+1][ch]} ----
        const unsigned short* xbase = xb + (lane & 15);
        unsigned bw0[4][4], bw1[4][4];
#pragma unroll
        for (int d = 0; d < 4; ++d) {
            const unsigned short* pLo0 = xbase + (size_t)src0[2 * d]     * C_DIM;
            const unsigned short* pHi0 = xbase + (size_t)src0[2 * d + 1] * C_DIM;
            const unsigned short* pLo1 = xbase + (size_t)src1[2 * d]     * C_DIM;
            const unsigned short* pHi1 = xbase + (size_t)src1[2 * d + 1] * C_DIM;
#pragma unroll
            for (int g = 0; g < 4; ++g) {
                unsigned lo0 = pLo0[g * 16], hi0 = pHi0[g * 16];
                unsigned lo1 = pLo1[g * 16], hi1 = pHi1[g * 16];
                bw0[g][d] = lo0 | (hi0 << 16);
                bw1[g][d] = lo1 | (hi1 << 16);
            }
        }

        // ---- A-frag (indicator * 1/cnt) + 8 binning MFMAs ----
        const unsigned rl    = lane & 7;
        const bool     hi_ok = (lane >> 5) == ((lane & 15) >> 3);
#pragma unroll
        for (int pr = 0; pr < 2; ++pr) {
            const unsigned char* relp = &rel_lds[w][pr * 32 + q8];
            unsigned rlo = *(const unsigned*)relp;
            unsigned rhi = *(const unsigned*)(relp + 4);
            unsigned inv16 = inv_lds[w][(pr * 2 + ((lane & 15) >> 3)) * 8 + (lane & 7)];
            unsigned invg  = hi_ok ? inv16 : 0u;
            unsigned af[4];
#pragma unroll
            for (int d = 0; d < 4; ++d) {
                unsigned wrd = (d < 2) ? rlo : rhi;
                unsigned b0 = (wrd >> ((d & 1) * 16)) & 0xFFu;
                unsigned b1 = (wrd >> ((d & 1) * 16 + 8)) & 0xFFu;
                af[d] = (b0 == rl ? invg : 0u) | ((b1 == rl ? invg : 0u) << 16);
            }
            union { unsigned u[4]; bf16x8 v; } au;
            au.u[0] = af[0]; au.u[1] = af[1]; au.u[2] = af[2]; au.u[3] = af[3];

#pragma unroll
            for (int g = 0; g < 4; ++g) {
                union { unsigned u[4]; bf16x8 v; } bu;
                if (pr == 0) {
                    bu.u[0] = bw0[g][0]; bu.u[1] = bw0[g][1];
                    bu.u[2] = bw0[g][2]; bu.u[3] = bw0[g][3];
                } else {
                    bu.u[0] = bw1[g][0]; bu.u[1] = bw1[g][1];
                    bu.u[2] = bw1[g][2]; bu.u[3] = bw1[g][3];
                }
                f32x4 dacc = __builtin_amdgcn_mfma_f32_16x16x32_bf16(
                                 au.v, bu.v, (f32x4){0.f, 0.f, 0.f, 0.f}, 0, 0, 0);
#pragma unroll
                for (int reg = 0; reg < 4; ++reg) {
                    int m = (lane >> 4) * 4 + reg;        // (node_in_pair, rel)
                    xa[w * 4 + pr * 2 + (m >> 3)][(m & 7) * C_DIM + g * 16 + (lane & 15)]
                        = f2bf(dacc[reg]);
                }
            }
        }
    } else {
        // ---- general path (variable degree / no bf16 buffer) ----
        for (int mi_ = 0; mi_ < 4; ++mi_) {
            const int mi = w * 4 + mi_;
            const int n  = nbase + mi_;
            const int sdeg  = __builtin_amdgcn_readlane(deg_l, mi_ * 16);
            const int sbase = __builtin_amdgcn_readlane(rp0,   mi_ * 16);
            if (sdeg < 0) {
                for (int k = lane; k < K_DIM; k += 64) xa[mi][k] = 0;
                continue;
            }
            float s0=0,s1=0,s2=0,s3=0,s4=0,s5=0,s6=0,s7=0;
            int   c0=0,c1=0,c2=0,c3=0,c4=0,c5=0,c6=0,c7=0;
            for (int e = 0; e < sdeg; ++e) {
                int src = col_ind[sbase + e];
                int rlv = edge_type[sbase + e];
                float vv = USE_BF ? bf2f(xb[(size_t)src * C_DIM + lane])
                                  : x_feat[(size_t)src * C_DIM + lane];
                ACCUM_SWITCH(rlv, vv)
            }
            xa[mi][0*C_DIM+lane] = f2bf(s0 * __fdividef(1.0f, (float)(c0>0?c0:1)));
            xa[mi][1*C_DIM+lane] = f2bf(s1 * __fdividef(1.0f, (float)(c1>0?c1:1)));
            xa[mi][2*C_DIM+lane] = f2bf(s2 * __fdividef(1.0f, (float)(c2>0?c2:1)));
            xa[mi][3*C_DIM+lane] = f2bf(s3 * __fdividef(1.0f, (float)(c3>0?c3:1)));
            xa[mi][4*C_DIM+lane] = f2bf(s4 * __fdividef(1.0f, (float)(c4>0?c4:1)));
            xa[mi][5*C_DIM+lane] = f2bf(s5 * __fdividef(1.0f, (float)(c5>0?c5:1)));
            xa[mi][6*C_DIM+lane] = f2bf(s6 * __fdividef(1.0f, (float)(c6>0?c6:1)));
            xa[mi][7*C_DIM+lane] = f2bf(s7 * __fdividef(1.0f, (float)(c7>0?c7:1)));
            xa[mi][8*C_DIM+lane] = USE_BF ? (unsigned short)xb[(size_t)n * C_DIM + lane]
                                          : f2bf(x_feat[(size_t)n * C_DIM + lane]);
        }
    }
    __syncthreads();

    // ---- phase 2: [16 x 576] @ [576 x 64]; wave w owns C-tile ct=w ----
    const int ct   = w;
    f32x4 acc = {0,0,0,0};
    const int arow = lane & 15;
    const int kgrp2 = lane >> 4;
    const bf16x8* wf8 = (const bf16x8*)wfrag;
#pragma unroll
    for (int kt = 0; kt < KT_N; ++kt) {
        bf16x8 a = *(const bf16x8*)&xa[arow][kt * 32 + kgrp2 * 8];
        acc = __builtin_amdgcn_mfma_f32_16x16x32_bf16(a, wf8[(kt*4 + ct)*64 + lane], acc, 0,0,0);
    }

    // ---- epilogue ----
    const int col   = ct * 16 + (lane & 15);
    const float b   = bias[col];
    const int rbase = (lane >> 4) * 4;
#pragma unroll
    for (int j = 0; j < 4; ++j) {
        int n = m0 + rbase + j;
        if (n < n_nodes)
            out[n * C_DIM + col] = acc[j] + b;
    }
}

extern "C" void kernel_launch(void* const* d_in, const int* in_sizes, int n_in,
                              void* d_out, int out_size, void* d_ws, size_t ws_size,
                              hipStream_t stream) {
    const float* x_feat    = (const float*)d_in[0];
    const float* weight    = (const float*)d_in[1];
    const float* bias      = (const float*)d_in[2];
    const int*   row_ptr   = (const int*)d_in[3];
    const int*   col_ind   = (const int*)d_in[4];
    const int*   edge_type = (const int*)d_in[5];
    float* out = (float*)d_out;

    const int n_nodes = in_sizes[3] - 1;
    const int nblocks = (n_nodes + TILE_M - 1) / TILE_M;

    unsigned int* wfrag = (unsigned int*)d_ws;              // 73728 bytes
    const size_t wf_bytes = (size_t)KT_N * CT_N * 64 * 16;  // 73728
    const size_t xb_bytes = (size_t)n_nodes * C_DIM * 2;

    pack_w_kernel<<<(KT_N * CT_N * 64 + 255) / 256, 256, 0, stream>>>(weight, wfrag);

    if (ws_size >= wf_bytes + xb_bytes) {
        unsigned short* xb = (unsigned short*)((char*)d_ws + wf_bytes);
        int n4 = n_nodes * C_DIM / 4;
        cvt_x_kernel<<<(n4 + 255) / 256, 256, 0, stream>>>(x_feat, xb, n4);
        rgcn_kernel<1><<<nblocks, 256, 0, stream>>>(x_feat, xb, bias, row_ptr, col_ind,
                                                    edge_type, (const unsigned short*)d_ws,
                                                    out, n_nodes);
    } else {
        rgcn_kernel<0><<<nblocks, 256, 0, stream>>>(x_feat, nullptr, bias, row_ptr, col_ind,
                                                    edge_type, (const unsigned short*)d_ws,
                                                    out, n_nodes);
    }
}

// Round 8
// 56.438 us; speedup vs baseline: 10.2722x; 1.0507x over previous
//
#include <hip/hip_runtime.h>
#include <hip/hip_bf16.h>

#define R_REL   8
#define C_DIM   64
#define K_DIM   576      // (R_REL+1)*C_DIM
#define KT_N    18       // K_DIM / 32
#define CT_N    4        // C_DIM / 16
#define TILE_M  16
#define K_PAD   584      // 576 + 8 bf16 pad -> row stride 1168 B (73*16B)

typedef __attribute__((ext_vector_type(8))) short bf16x8;
typedef __attribute__((ext_vector_type(4))) float f32x4;
typedef __attribute__((ext_vector_type(2))) unsigned u32x2;

// xb channel interleave: i'(ch) = (ch&15)*4 + (ch>>4); ch(j) = (j&3)*16 + (j>>2)

static __device__ __forceinline__ unsigned short f2bf(float f) {
    union { float f; unsigned u; } v; v.f = f;
    unsigned r = v.u + 0x7FFFu + ((v.u >> 16) & 1u);   // RNE
    return (unsigned short)(r >> 16);
}
static __device__ __forceinline__ float bf2f(unsigned u16) {
    union { unsigned u; float f; } v; v.u = u16 << 16;
    return v.f;
}

// Pack W [9][64][64] f32 -> bf16 MFMA B-fragments.
// K positions >= 512 are remapped to match xb's interleaved self block.
__global__ void pack_w_kernel(const float* __restrict__ w, unsigned int* __restrict__ wf) {
    int t = blockIdx.x * blockDim.x + threadIdx.x;
    if (t >= KT_N * CT_N * 64) return;
    int lane = t & 63;
    int ct   = (t >> 6) & 3;
    int kt   = t >> 8;
    int row0 = kt * 32 + (lane >> 4) * 8;
    int col  = ct * 16 + (lane & 15);
    unsigned short v[8];
#pragma unroll
    for (int j = 0; j < 8; ++j) {
        int rk = row0 + j;
        int wr = (rk < 512) ? rk : 512 + ((rk - 512) & 3) * 16 + ((rk - 512) >> 2);
        v[j] = f2bf(w[wr * C_DIM + col]);
    }
    uint4 o;
    o.x = (unsigned)v[0] | ((unsigned)v[1] << 16);
    o.y = (unsigned)v[2] | ((unsigned)v[3] << 16);
    o.z = (unsigned)v[4] | ((unsigned)v[5] << 16);
    o.w = (unsigned)v[6] | ((unsigned)v[7] << 16);
    ((uint4*)wf)[t] = o;
}

// x_feat f32 -> bf16, channel-interleaved: xb[n][ (ch&15)*4 + (ch>>4) ] = x[n][ch].
// Thread t = n*16 + c writes channels {c, 16+c, 32+c, 48+c} as one 8B store.
__global__ void cvt_x_kernel(const float* __restrict__ x, unsigned short* __restrict__ xb,
                             int total) {
    int t = blockIdx.x * blockDim.x + threadIdx.x;
    if (t >= total) return;
    int n = t >> 4, c = t & 15;
    const float* xr = x + (size_t)n * C_DIM + c;
    ushort4 o;
    o.x = f2bf(xr[0]);
    o.y = f2bf(xr[16]);
    o.z = f2bf(xr[32]);
    o.w = f2bf(xr[48]);
    *(ushort4*)(xb + (size_t)n * C_DIM + c * 4) = o;
}

#define ACCUM_SWITCH(RELV, VV)                                  \
    switch (RELV) {                                             \
        case 0: s0 += (VV); ++c0; break;                        \
        case 1: s1 += (VV); ++c1; break;                        \
        case 2: s2 += (VV); ++c2; break;                        \
        case 3: s3 += (VV); ++c3; break;                        \
        case 4: s4 += (VV); ++c4; break;                        \
        case 5: s5 += (VV); ++c5; break;                        \
        case 6: s6 += (VV); ++c6; break;                        \
        default: s7 += (VV); ++c7; break;                       \
    }

template<int USE_BF>
__global__ __launch_bounds__(256, 8) void rgcn_kernel(
    const float* __restrict__ x_feat,
    const unsigned short* __restrict__ xb,
    const float* __restrict__ bias,
    const int*   __restrict__ row_ptr,
    const int*   __restrict__ col_ind,
    const int*   __restrict__ edge_type,
    const unsigned short* __restrict__ wfrag,
    float* __restrict__ out,
    int n_nodes)
{
    __shared__ __align__(16) unsigned short xa[TILE_M][K_PAD];   // 18.7 KB
    __shared__ __align__(16) int            col_lds[4][64];      // 1 KB
    __shared__ __align__(8)  unsigned char  rel_lds[4][64];      // 256 B
    __shared__ __align__(4)  unsigned short inv_lds[4][32];      // 256 B

    const int tid   = threadIdx.x;
    const int lane  = tid & 63;
    const int w     = tid >> 6;            // wave id 0..3
    const int m0    = blockIdx.x * TILE_M;
    const int nbase = m0 + w * 4;          // this wave's 4 nodes

    // ---- per-lane meta: lane = local_node(2b)*16 + edge_slot(4b) ----
    const int n_l   = nbase + (lane >> 4);
    const bool v_l  = n_l < n_nodes;
    int rp0   = v_l ? row_ptr[n_l]     : 0;
    int rp1   = v_l ? row_ptr[n_l + 1] : 0;
    int deg_l = v_l ? (rp1 - rp0) : -1;
    int col_l = col_ind[rp0 + (lane & 15)];
    int rel_l = edge_type[rp0 + (lane & 15)];

    const bool fast = USE_BF && (__ballot(deg_l == 16) == ~0ull);

    if (fast) {
        // ---- publish per-wave edge tables ----
        col_lds[w][lane] = col_l;
        rel_lds[w][lane] = (unsigned char)rel_l;
        unsigned long long bsel = 0;
#pragma unroll
        for (int r = 0; r < 8; ++r) {
            unsigned long long b = __ballot(rel_l == r);
            bsel = ((lane & 7) == r) ? b : bsel;
        }
        if (lane < 32) {
            int nd  = (lane >> 3) & 3;
            int cnt = __popcll(bsel & (0xFFFFull << (nd * 16)));
            inv_lds[w][lane] = f2bf(1.0f / (float)(cnt > 0 ? cnt : 1));
        }

        // ---- self row straight into xa (interleaved block matches pack_w remap) ----
        u32x2 selfv = *(const u32x2*)(xb + (size_t)(nbase + (lane >> 4)) * C_DIM
                                      + (lane & 15) * 4);
        *(u32x2*)&xa[w * 4 + (lane >> 4)][8 * C_DIM + (lane & 15) * 4] = selfv;

        // ---- read back the 16 src indices this lane's B-fragments need ----
        const int q8 = (lane >> 4) * 8;
        int4 c0a = *(const int4*)&col_lds[w][q8];
        int4 c0b = *(const int4*)&col_lds[w][q8 + 4];
        int4 c1a = *(const int4*)&col_lds[w][32 + q8];
        int4 c1b = *(const int4*)&col_lds[w][32 + q8 + 4];
        int src0[8] = {c0a.x, c0a.y, c0a.z, c0a.w, c0b.x, c0b.y, c0b.z, c0b.w};
        int src1[8] = {c1a.x, c1a.y, c1a.z, c1a.w, c1b.x, c1b.y, c1b.z, c1b.w};

        // ---- B-fragment gather: one dwordx2 per row = 4 channels (g=0..3) ----
        const unsigned short* xbase = xb + (lane & 15) * 4;
        u32x2 gv0[8], gv1[8];
#pragma unroll
        for (int e = 0; e < 8; ++e) {
            gv0[e] = *(const u32x2*)(xbase + (size_t)src0[e] * C_DIM);
            gv1[e] = *(const u32x2*)(xbase + (size_t)src1[e] * C_DIM);
        }

        // ---- pack (lo,hi) bf16 pairs: bw[g][d] = {X[e=2d][g], X[e=2d+1][g]} ----
        unsigned bw0[4][4], bw1[4][4];
#pragma unroll
        for (int d = 0; d < 4; ++d) {
            unsigned lx = gv0[2*d].x, hx = gv0[2*d+1].x;
            unsigned ly = gv0[2*d].y, hy = gv0[2*d+1].y;
            bw0[0][d] = (lx & 0xFFFFu) | (hx << 16);
            bw0[1][d] = (lx >> 16)     | (hx & 0xFFFF0000u);
            bw0[2][d] = (ly & 0xFFFFu) | (hy << 16);
            bw0[3][d] = (ly >> 16)     | (hy & 0xFFFF0000u);
            lx = gv1[2*d].x; hx = gv1[2*d+1].x;
            ly = gv1[2*d].y; hy = gv1[2*d+1].y;
            bw1[0][d] = (lx & 0xFFFFu) | (hx << 16);
            bw1[1][d] = (lx >> 16)     | (hx & 0xFFFF0000u);
            bw1[2][d] = (ly & 0xFFFFu) | (hy << 16);
            bw1[3][d] = (ly >> 16)     | (hy & 0xFFFF0000u);
        }

        // ---- A-frag (indicator * 1/cnt) + 8 binning MFMAs ----
        const unsigned rl    = lane & 7;
        const bool     hi_ok = (lane >> 5) == ((lane & 15) >> 3);
#pragma unroll
        for (int pr = 0; pr < 2; ++pr) {
            const unsigned char* relp = &rel_lds[w][pr * 32 + q8];
            unsigned rlo = *(const unsigned*)relp;
            unsigned rhi = *(const unsigned*)(relp + 4);
            unsigned inv16 = inv_lds[w][(pr * 2 + ((lane & 15) >> 3)) * 8 + (lane & 7)];
            unsigned invg  = hi_ok ? inv16 : 0u;
            unsigned af[4];
#pragma unroll
            for (int d = 0; d < 4; ++d) {
                unsigned wrd = (d < 2) ? rlo : rhi;
                unsigned b0 = (wrd >> ((d & 1) * 16)) & 0xFFu;
                unsigned b1 = (wrd >> ((d & 1) * 16 + 8)) & 0xFFu;
                af[d] = (b0 == rl ? invg : 0u) | ((b1 == rl ? invg : 0u) << 16);
            }
            union { unsigned u[4]; bf16x8 v; } au;
            au.u[0] = af[0]; au.u[1] = af[1]; au.u[2] = af[2]; au.u[3] = af[3];

#pragma unroll
            for (int g = 0; g < 4; ++g) {
                union { unsigned u[4]; bf16x8 v; } bu;
                if (pr == 0) {
                    bu.u[0] = bw0[g][0]; bu.u[1] = bw0[g][1];
                    bu.u[2] = bw0[g][2]; bu.u[3] = bw0[g][3];
                } else {
                    bu.u[0] = bw1[g][0]; bu.u[1] = bw1[g][1];
                    bu.u[2] = bw1[g][2]; bu.u[3] = bw1[g][3];
                }
                f32x4 dacc = __builtin_amdgcn_mfma_f32_16x16x32_bf16(
                                 au.v, bu.v, (f32x4){0.f, 0.f, 0.f, 0.f}, 0, 0, 0);
#pragma unroll
                for (int reg = 0; reg < 4; ++reg) {
                    int m = (lane >> 4) * 4 + reg;        // (node_in_pair, rel)
                    xa[w * 4 + pr * 2 + (m >> 3)][(m & 7) * C_DIM + g * 16 + (lane & 15)]
                        = f2bf(dacc[reg]);
                }
            }
        }
    } else {
        // ---- general path (variable degree / no bf16 buffer) ----
        for (int mi_ = 0; mi_ < 4; ++mi_) {
            const int mi = w * 4 + mi_;
            const int n  = nbase + mi_;
            const int sdeg  = __builtin_amdgcn_readlane(deg_l, mi_ * 16);
            const int sbase = __builtin_amdgcn_readlane(rp0,   mi_ * 16);
            if (sdeg < 0) {
                for (int k = lane; k < K_DIM; k += 64) xa[mi][k] = 0;
                continue;
            }
            float s0=0,s1=0,s2=0,s3=0,s4=0,s5=0,s6=0,s7=0;
            int   c0=0,c1=0,c2=0,c3=0,c4=0,c5=0,c6=0,c7=0;
            const int ich = (lane & 15) * 4 + (lane >> 4);   // i'(ch=lane) in xb
            for (int e = 0; e < sdeg; ++e) {
                int src = col_ind[sbase + e];
                int rlv = edge_type[sbase + e];
                float vv = USE_BF ? bf2f(xb[(size_t)src * C_DIM + ich])
                                  : x_feat[(size_t)src * C_DIM + lane];
                ACCUM_SWITCH(rlv, vv)
            }
            xa[mi][0*C_DIM+lane] = f2bf(s0 * __fdividef(1.0f, (float)(c0>0?c0:1)));
            xa[mi][1*C_DIM+lane] = f2bf(s1 * __fdividef(1.0f, (float)(c1>0?c1:1)));
            xa[mi][2*C_DIM+lane] = f2bf(s2 * __fdividef(1.0f, (float)(c2>0?c2:1)));
            xa[mi][3*C_DIM+lane] = f2bf(s3 * __fdividef(1.0f, (float)(c3>0?c3:1)));
            xa[mi][4*C_DIM+lane] = f2bf(s4 * __fdividef(1.0f, (float)(c4>0?c4:1)));
            xa[mi][5*C_DIM+lane] = f2bf(s5 * __fdividef(1.0f, (float)(c5>0?c5:1)));
            xa[mi][6*C_DIM+lane] = f2bf(s6 * __fdividef(1.0f, (float)(c6>0?c6:1)));
            xa[mi][7*C_DIM+lane] = f2bf(s7 * __fdividef(1.0f, (float)(c7>0?c7:1)));
            // self block: position 512+lane must hold channel ch(lane)=(lane&3)*16+(lane>>2)
            xa[mi][8*C_DIM+lane] = USE_BF ? (unsigned short)xb[(size_t)n * C_DIM + lane]
                                          : f2bf(x_feat[(size_t)n * C_DIM
                                                        + (lane & 3) * 16 + (lane >> 2)]);
        }
    }
    __syncthreads();

    // ---- phase 2: [16 x 576] @ [576 x 64]; wave w owns C-tile ct=w ----
    const int ct   = w;
    f32x4 acc = {0,0,0,0};
    const int arow = lane & 15;
    const int kgrp2 = lane >> 4;
    const bf16x8* wf8 = (const bf16x8*)wfrag;
#pragma unroll
    for (int kt = 0; kt < KT_N; ++kt) {
        bf16x8 a = *(const bf16x8*)&xa[arow][kt * 32 + kgrp2 * 8];
        acc = __builtin_amdgcn_mfma_f32_16x16x32_bf16(a, wf8[(kt*4 + ct)*64 + lane], acc, 0,0,0);
    }

    // ---- epilogue ----
    const int col   = ct * 16 + (lane & 15);
    const float b   = bias[col];
    const int rbase = (lane >> 4) * 4;
#pragma unroll
    for (int j = 0; j < 4; ++j) {
        int n = m0 + rbase + j;
        if (n < n_nodes)
            out[n * C_DIM + col] = acc[j] + b;
    }
}

extern "C" void kernel_launch(void* const* d_in, const int* in_sizes, int n_in,
                              void* d_out, int out_size, void* d_ws, size_t ws_size,
                              hipStream_t stream) {
    const float* x_feat    = (const float*)d_in[0];
    const float* weight    = (const float*)d_in[1];
    const float* bias      = (const float*)d_in[2];
    const int*   row_ptr   = (const int*)d_in[3];
    const int*   col_ind   = (const int*)d_in[4];
    const int*   edge_type = (const int*)d_in[5];
    float* out = (float*)d_out;

    const int n_nodes = in_sizes[3] - 1;
    const int nblocks = (n_nodes + TILE_M - 1) / TILE_M;

    unsigned int* wfrag = (unsigned int*)d_ws;              // 73728 bytes
    const size_t wf_bytes = (size_t)KT_N * CT_N * 64 * 16;  // 73728
    const size_t xb_bytes = (size_t)n_nodes * C_DIM * 2;

    pack_w_kernel<<<(KT_N * CT_N * 64 + 255) / 256, 256, 0, stream>>>(weight, wfrag);

    if (ws_size >= wf_bytes + xb_bytes) {
        unsigned short* xb = (unsigned short*)((char*)d_ws + wf_bytes);
        int total = n_nodes * 16;
        cvt_x_kernel<<<(total + 255) / 256, 256, 0, stream>>>(x_feat, xb, total);
        rgcn_kernel<1><<<nblocks, 256, 0, stream>>>(x_feat, xb, bias, row_ptr, col_ind,
                                                    edge_type, (const unsigned short*)d_ws,
                                                    out, n_nodes);
    } else {
        rgcn_kernel<0><<<nblocks, 256, 0, stream>>>(x_feat, nullptr, bias, row_ptr, col_ind,
                                                    edge_type, (const unsigned short*)d_ws,
                                                    out, n_nodes);
    }
}

// Round 9
// 51.563 us; speedup vs baseline: 11.2435x; 1.0945x over previous
//
#include <hip/hip_runtime.h>
#include <hip/hip_bf16.h>

#define R_REL   8
#define C_DIM   64
#define K_DIM   576      // (R_REL+1)*C_DIM
#define KT_N    18       // K_DIM / 32
#define CT_N    4        // C_DIM / 16
#define TILE_M  16
#define K_PAD   584      // 576 + 8 bf16 pad -> row stride 1168 B (73*16B)
#define PACK_T  (KT_N * CT_N * 64)   // 4608 pack_w threads

typedef __attribute__((ext_vector_type(8))) short bf16x8;
typedef __attribute__((ext_vector_type(4))) float f32x4;
typedef __attribute__((ext_vector_type(2))) unsigned u32x2;

// xb channel interleave: i'(ch) = (ch&15)*4 + (ch>>4); ch(j) = (j&3)*16 + (j>>2)
// agg K-permutation:  k'(rel,ch) = (ch>>4)*128 + (ch&15)*8 + rel   (k' < 512)
// self K region:      k' = 512 + i'(ch)                            (unchanged)

static __device__ __forceinline__ unsigned short f2bf(float f) {
    union { float f; unsigned u; } v; v.f = f;
    unsigned r = v.u + 0x7FFFu + ((v.u >> 16) & 1u);   // RNE
    return (unsigned short)(r >> 16);
}
static __device__ __forceinline__ float bf2f(unsigned u16) {
    union { unsigned u; float f; } v; v.u = u16 << 16;
    return v.f;
}

// Fused prep: blocks 0..17 pack W fragments; the rest convert x_feat -> xb.
__global__ void prep_kernel(const float* __restrict__ x, const float* __restrict__ wt,
                            unsigned short* __restrict__ xb, unsigned int* __restrict__ wf,
                            int total_cvt) {
    int t = blockIdx.x * 256 + threadIdx.x;
    if (t < PACK_T) {
        int lane = t & 63;
        int ct   = (t >> 6) & 3;
        int kt   = t >> 8;
        int row0 = kt * 32 + (lane >> 4) * 8;
        int col  = ct * 16 + (lane & 15);
        unsigned short v[8];
#pragma unroll
        for (int j = 0; j < 8; ++j) {
            int rk = row0 + j;
            int wr;
            if (rk < 512) {
                int rel = rk & 7, c = (rk >> 3) & 15, g = rk >> 7;
                wr = rel * C_DIM + g * 16 + c;              // original k = rel*64 + ch
            } else {
                wr = 512 + ((rk - 512) & 3) * 16 + ((rk - 512) >> 2);
            }
            v[j] = f2bf(wt[wr * C_DIM + col]);
        }
        uint4 o;
        o.x = (unsigned)v[0] | ((unsigned)v[1] << 16);
        o.y = (unsigned)v[2] | ((unsigned)v[3] << 16);
        o.z = (unsigned)v[4] | ((unsigned)v[5] << 16);
        o.w = (unsigned)v[6] | ((unsigned)v[7] << 16);
        ((uint4*)wf)[t] = o;
        return;
    }
    int tc = t - PACK_T;
    if (tc >= total_cvt) return;
    int n = tc >> 4, c = tc & 15;
    const float* xr = x + (size_t)n * C_DIM + c;
    ushort4 o;
    o.x = f2bf(xr[0]);
    o.y = f2bf(xr[16]);
    o.z = f2bf(xr[32]);
    o.w = f2bf(xr[48]);
    *(ushort4*)(xb + (size_t)n * C_DIM + c * 4) = o;
}

#define ACCUM_SWITCH(RELV, VV)                                  \
    switch (RELV) {                                             \
        case 0: s0 += (VV); ++c0; break;                        \
        case 1: s1 += (VV); ++c1; break;                        \
        case 2: s2 += (VV); ++c2; break;                        \
        case 3: s3 += (VV); ++c3; break;                        \
        case 4: s4 += (VV); ++c4; break;                        \
        case 5: s5 += (VV); ++c5; break;                        \
        case 6: s6 += (VV); ++c6; break;                        \
        default: s7 += (VV); ++c7; break;                       \
    }

template<int USE_BF>
__global__ __launch_bounds__(256, 8) void rgcn_kernel(
    const float* __restrict__ x_feat,
    const unsigned short* __restrict__ xb,
    const float* __restrict__ bias,
    const int*   __restrict__ row_ptr,
    const int*   __restrict__ col_ind,
    const int*   __restrict__ edge_type,
    const unsigned short* __restrict__ wfrag,
    float* __restrict__ out,
    int n_nodes)
{
    __shared__ __align__(16) unsigned short xa[TILE_M][K_PAD];   // 18.7 KB
    __shared__ __align__(8)  unsigned char  rel_lds[4][64];      // 256 B
    __shared__ __align__(4)  unsigned short inv_lds[4][32];      // 256 B

    const int tid   = threadIdx.x;
    const int lane  = tid & 63;
    const int w     = tid >> 6;            // wave id 0..3
    const int m0    = blockIdx.x * TILE_M;
    const int nbase = m0 + w * 4;          // this wave's 4 nodes

    // ---- per-lane meta: lane = local_node(2b)*16 + edge_slot(4b) ----
    const int n_l   = nbase + (lane >> 4);
    const bool v_l  = n_l < n_nodes;
    int rp0   = v_l ? row_ptr[n_l]     : 0;
    int rp1   = v_l ? row_ptr[n_l + 1] : 0;
    int deg_l = v_l ? (rp1 - rp0) : -1;
    int col_l = col_ind[rp0 + (lane & 15)];
    int rel_l = edge_type[rp0 + (lane & 15)];

    const bool fast = USE_BF && (__ballot(deg_l == 16) == ~0ull);

    if (fast) {
        // ---- publish rel table + inverse counts ----
        rel_lds[w][lane] = (unsigned char)rel_l;
        unsigned long long bsel = 0;
#pragma unroll
        for (int r = 0; r < 8; ++r) {
            unsigned long long b = __ballot(rel_l == r);
            bsel = ((lane & 7) == r) ? b : bsel;
        }
        if (lane < 32) {
            int nd  = (lane >> 3) & 3;
            int cnt = __popcll(bsel & (0xFFFFull << (nd * 16)));
            inv_lds[w][lane] = f2bf(1.0f / (float)(cnt > 0 ? cnt : 1));
        }

        // ---- self row straight into xa ----
        u32x2 selfv = *(const u32x2*)(xb + (size_t)(nbase + (lane >> 4)) * C_DIM
                                      + (lane & 15) * 4);
        *(u32x2*)&xa[w * 4 + (lane >> 4)][8 * C_DIM + (lane & 15) * 4] = selfv;

        // ---- src indices via bpermute (edge (lane>>4)*8+e of node pairs) ----
        const int q   = lane >> 4;
        const int q8b = q << 5;                       // (q*8)*4 bytes
        int src0[8], src1[8];
#pragma unroll
        for (int e = 0; e < 8; ++e) {
            src0[e] = __builtin_amdgcn_ds_bpermute(q8b + e * 4,       col_l);
            src1[e] = __builtin_amdgcn_ds_bpermute(q8b + 128 + e * 4, col_l);
        }

        // ---- B-fragment gather: one dwordx2 per row = 4 channels (g=0..3) ----
        const unsigned short* xbase = xb + (lane & 15) * 4;
        u32x2 gv0[8], gv1[8];
#pragma unroll
        for (int e = 0; e < 8; ++e) {
            gv0[e] = *(const u32x2*)(xbase + (size_t)src0[e] * C_DIM);
            gv1[e] = *(const u32x2*)(xbase + (size_t)src1[e] * C_DIM);
        }

        // ---- pack (lo,hi) bf16 pairs: bw[g][d] = {X[e=2d][g], X[e=2d+1][g]} ----
        unsigned bw0[4][4], bw1[4][4];
#pragma unroll
        for (int d = 0; d < 4; ++d) {
            unsigned lx = gv0[2*d].x, hx = gv0[2*d+1].x;
            unsigned ly = gv0[2*d].y, hy = gv0[2*d+1].y;
            bw0[0][d] = (lx & 0xFFFFu) | (hx << 16);
            bw0[1][d] = (lx >> 16)     | (hx & 0xFFFF0000u);
            bw0[2][d] = (ly & 0xFFFFu) | (hy << 16);
            bw0[3][d] = (ly >> 16)     | (hy & 0xFFFF0000u);
            lx = gv1[2*d].x; hx = gv1[2*d+1].x;
            ly = gv1[2*d].y; hy = gv1[2*d+1].y;
            bw1[0][d] = (lx & 0xFFFFu) | (hx << 16);
            bw1[1][d] = (lx >> 16)     | (hx & 0xFFFF0000u);
            bw1[2][d] = (ly & 0xFFFFu) | (hy << 16);
            bw1[3][d] = (ly >> 16)     | (hy & 0xFFFF0000u);
        }

        // ---- A-frag (indicator * 1/cnt) + 8 binning MFMAs ----
        const unsigned rl    = lane & 7;
        const bool     hi_ok = (lane >> 5) == ((lane & 15) >> 3);
        const int rb   = (q & 1) * 4;                 // rel base of this lane's D rows
        const int nrow = q >> 1;                      // node-in-pair of D rows
#pragma unroll
        for (int pr = 0; pr < 2; ++pr) {
            const unsigned char* relp = &rel_lds[w][pr * 32 + q * 8];
            unsigned rlo = *(const unsigned*)relp;
            unsigned rhi = *(const unsigned*)(relp + 4);
            unsigned inv16 = inv_lds[w][(pr * 2 + ((lane & 15) >> 3)) * 8 + (lane & 7)];
            unsigned invg  = hi_ok ? inv16 : 0u;
            unsigned af[4];
#pragma unroll
            for (int d = 0; d < 4; ++d) {
                unsigned wrd = (d < 2) ? rlo : rhi;
                unsigned b0 = (wrd >> ((d & 1) * 16)) & 0xFFu;
                unsigned b1 = (wrd >> ((d & 1) * 16 + 8)) & 0xFFu;
                af[d] = (b0 == rl ? invg : 0u) | ((b1 == rl ? invg : 0u) << 16);
            }
            union { unsigned u[4]; bf16x8 v; } au;
            au.u[0] = af[0]; au.u[1] = af[1]; au.u[2] = af[2]; au.u[3] = af[3];

            unsigned short* xrow = &xa[w * 4 + pr * 2 + nrow][(lane & 15) * 8 + rb];
#pragma unroll
            for (int g = 0; g < 4; ++g) {
                union { unsigned u[4]; bf16x8 v; } bu;
                if (pr == 0) {
                    bu.u[0] = bw0[g][0]; bu.u[1] = bw0[g][1];
                    bu.u[2] = bw0[g][2]; bu.u[3] = bw0[g][3];
                } else {
                    bu.u[0] = bw1[g][0]; bu.u[1] = bw1[g][1];
                    bu.u[2] = bw1[g][2]; bu.u[3] = bw1[g][3];
                }
                f32x4 dacc = __builtin_amdgcn_mfma_f32_16x16x32_bf16(
                                 au.v, bu.v, (f32x4){0.f, 0.f, 0.f, 0.f}, 0, 0, 0);
                // paired store: rels rb+0..3 are consecutive in k' => two 4B writes
                unsigned w0p = (unsigned)f2bf(dacc[0]) | ((unsigned)f2bf(dacc[1]) << 16);
                unsigned w1p = (unsigned)f2bf(dacc[2]) | ((unsigned)f2bf(dacc[3]) << 16);
                *(unsigned*)(xrow + g * 128)     = w0p;
                *(unsigned*)(xrow + g * 128 + 2) = w1p;
            }
        }
    } else {
        // ---- general path (variable degree / no bf16 buffer) ----
        for (int mi_ = 0; mi_ < 4; ++mi_) {
            const int mi = w * 4 + mi_;
            const int n  = nbase + mi_;
            const int sdeg  = __builtin_amdgcn_readlane(deg_l, mi_ * 16);
            const int sbase = __builtin_amdgcn_readlane(rp0,   mi_ * 16);
            if (sdeg < 0) {
                for (int k = lane; k < K_DIM; k += 64) xa[mi][k] = 0;
                continue;
            }
            float s0=0,s1=0,s2=0,s3=0,s4=0,s5=0,s6=0,s7=0;
            int   c0=0,c1=0,c2=0,c3=0,c4=0,c5=0,c6=0,c7=0;
            const int ich = (lane & 15) * 4 + (lane >> 4);   // i'(ch=lane) in xb
            for (int e = 0; e < sdeg; ++e) {
                int src = col_ind[sbase + e];
                int rlv = edge_type[sbase + e];
                float vv = USE_BF ? bf2f(xb[(size_t)src * C_DIM + ich])
                                  : x_feat[(size_t)src * C_DIM + lane];
                ACCUM_SWITCH(rlv, vv)
            }
            // k'(rel, ch=lane) = (lane>>4)*128 + (lane&15)*8 + rel
            const int kb = (lane >> 4) * 128 + (lane & 15) * 8;
            xa[mi][kb + 0] = f2bf(s0 * __fdividef(1.0f, (float)(c0>0?c0:1)));
            xa[mi][kb + 1] = f2bf(s1 * __fdividef(1.0f, (float)(c1>0?c1:1)));
            xa[mi][kb + 2] = f2bf(s2 * __fdividef(1.0f, (float)(c2>0?c2:1)));
            xa[mi][kb + 3] = f2bf(s3 * __fdividef(1.0f, (float)(c3>0?c3:1)));
            xa[mi][kb + 4] = f2bf(s4 * __fdividef(1.0f, (float)(c4>0?c4:1)));
            xa[mi][kb + 5] = f2bf(s5 * __fdividef(1.0f, (float)(c5>0?c5:1)));
            xa[mi][kb + 6] = f2bf(s6 * __fdividef(1.0f, (float)(c6>0?c6:1)));
            xa[mi][kb + 7] = f2bf(s7 * __fdividef(1.0f, (float)(c7>0?c7:1)));
            // self block: position 512+j holds channel ch(j)=(j&3)*16+(j>>2)
            xa[mi][8*C_DIM+lane] = USE_BF ? (unsigned short)xb[(size_t)n * C_DIM + lane]
                                          : f2bf(x_feat[(size_t)n * C_DIM
                                                        + (lane & 3) * 16 + (lane >> 2)]);
        }
    }
    __syncthreads();

    // ---- phase 2: [16 x 576] @ [576 x 64]; wave w owns C-tile ct=w ----
    const int ct   = w;
    f32x4 acc = {0,0,0,0};
    const int arow = lane & 15;
    const int kgrp2 = lane >> 4;
    const bf16x8* wf8 = (const bf16x8*)wfrag;
#pragma unroll
    for (int kt = 0; kt < KT_N; ++kt) {
        bf16x8 a = *(const bf16x8*)&xa[arow][kt * 32 + kgrp2 * 8];
        acc = __builtin_amdgcn_mfma_f32_16x16x32_bf16(a, wf8[(kt*4 + ct)*64 + lane], acc, 0,0,0);
    }

    // ---- epilogue ----
    const int col   = ct * 16 + (lane & 15);
    const float b   = bias[col];
    const int rbase = (lane >> 4) * 4;
#pragma unroll
    for (int j = 0; j < 4; ++j) {
        int n = m0 + rbase + j;
        if (n < n_nodes)
            out[n * C_DIM + col] = acc[j] + b;
    }
}

extern "C" void kernel_launch(void* const* d_in, const int* in_sizes, int n_in,
                              void* d_out, int out_size, void* d_ws, size_t ws_size,
                              hipStream_t stream) {
    const float* x_feat    = (const float*)d_in[0];
    const float* weight    = (const float*)d_in[1];
    const float* bias      = (const float*)d_in[2];
    const int*   row_ptr   = (const int*)d_in[3];
    const int*   col_ind   = (const int*)d_in[4];
    const int*   edge_type = (const int*)d_in[5];
    float* out = (float*)d_out;

    const int n_nodes = in_sizes[3] - 1;
    const int nblocks = (n_nodes + TILE_M - 1) / TILE_M;

    unsigned int* wfrag = (unsigned int*)d_ws;              // 73728 bytes
    const size_t wf_bytes = (size_t)PACK_T * 16;            // 73728
    const size_t xb_bytes = (size_t)n_nodes * C_DIM * 2;

    if (ws_size >= wf_bytes + xb_bytes) {
        unsigned short* xb = (unsigned short*)((char*)d_ws + wf_bytes);
        int total_cvt = n_nodes * 16;
        int prep_blocks = (PACK_T + total_cvt + 255) / 256;
        prep_kernel<<<prep_blocks, 256, 0, stream>>>(x_feat, weight, xb, wfrag, total_cvt);
        rgcn_kernel<1><<<nblocks, 256, 0, stream>>>(x_feat, xb, bias, row_ptr, col_ind,
                                                    edge_type, (const unsigned short*)d_ws,
                                                    out, n_nodes);
    } else {
        prep_kernel<<<(PACK_T + 255) / 256, 256, 0, stream>>>(x_feat, weight, nullptr, wfrag, 0);
        rgcn_kernel<0><<<nblocks, 256, 0, stream>>>(x_feat, nullptr, bias, row_ptr, col_ind,
                                                    edge_type, (const unsigned short*)d_ws,
                                                    out, n_nodes);
    }
}